// Round 15
// baseline (717.519 us; speedup 1.0000x reference)
//
#include <hip/hip_runtime.h>

#define CIN    32
#define COUT   32
#define KMAX   27
#define SCAN_B 2048

typedef _Float16 h2_t __attribute__((ext_vector_type(2)));

__device__ __forceinline__ float dot2(unsigned f, unsigned w, float a)
{
#if __has_builtin(__builtin_amdgcn_fdot2)
    return __builtin_amdgcn_fdot2(__builtin_bit_cast(h2_t, f),
                                  __builtin_bit_cast(h2_t, w), a, false);
#else
    h2_t ff = __builtin_bit_cast(h2_t, f), ww = __builtin_bit_cast(h2_t, w);
    return a + (float)ff.x * (float)ww.x + (float)ff.y * (float)ww.y;
#endif
}

__device__ __forceinline__ unsigned f2h2(float a, float b)
{
    unsigned short ua = __builtin_bit_cast(unsigned short, (_Float16)a);
    unsigned short ub = __builtin_bit_cast(unsigned short, (_Float16)b);
    return (unsigned)ua | ((unsigned)ub << 16);
}

// ---- fused prep: pack W (R6 layout), pack feat, build per-row k-mask ----
__global__ void k_fuse(const float* __restrict__ w, const float* __restrict__ f,
                       const int* __restrict__ scatter,
                       unsigned* __restrict__ wH, unsigned* __restrict__ fH,
                       unsigned* __restrict__ mask,
                       int K, int N, int npair, int M, int vec_ok)
{
    const int t0 = blockIdx.x * blockDim.x + threadIdx.x;
    const int stride = gridDim.x * blockDim.x;

    for (int i = t0; i < K * 512; i += stride) {
        int dj = i & 3, o = (i >> 2) & 31, j = (i >> 7) & 3, k = i >> 9;
        int i0 = 8 * j + 2 * dj;
        wH[i] = f2h2(w[(k * CIN + i0) * COUT + o], w[(k * CIN + i0 + 1) * COUT + o]);
    }
    for (int i = t0; i < N * 8; i += stride) {
        float4 v = ((const float4*)f)[i];
        uint2 r; r.x = f2h2(v.x, v.y); r.y = f2h2(v.z, v.w);
        ((uint2*)fH)[i] = r;
    }
    if (vec_ok) {
        const int npair4 = npair >> 2;
        const long long tot = (long long)K * npair4;
        for (long long t = t0; t < tot; t += stride) {
            int k = (int)(t / npair4), i = (int)(t - (long long)k * npair4);
            unsigned kb = 1u << k;
            int4 s4 = *(const int4*)(scatter + (size_t)k * npair + (size_t)i * 4);
            if (s4.x < M) atomicOr(&mask[s4.x], kb);
            if (s4.y < M) atomicOr(&mask[s4.y], kb);
            if (s4.z < M) atomicOr(&mask[s4.z], kb);
            if (s4.w < M) atomicOr(&mask[s4.w], kb);
        }
    } else {
        const long long tot = (long long)K * npair;
        for (long long t = t0; t < tot; t += stride) {
            int k = (int)(t / npair), i = (int)(t - (long long)k * npair);
            int s = scatter[(size_t)k * npair + i];
            if (s < M) atomicOr(&mask[s], 1u << k);
        }
    }
}

// ---- scan level 1 ----
__global__ void kb_scan1(const unsigned* __restrict__ mask, int* __restrict__ part, int n)
{
    __shared__ int red[256];
    int base = blockIdx.x * SCAN_B;
    int sum = 0;
    for (int i = threadIdx.x; i < SCAN_B; i += 256) {
        int idx = base + i;
        sum += (idx < n) ? __popc(mask[idx]) : 0;
    }
    red[threadIdx.x] = sum;
    __syncthreads();
    for (int s = 128; s > 0; s >>= 1) {
        if (threadIdx.x < s) red[threadIdx.x] += red[threadIdx.x + s];
        __syncthreads();
    }
    if (threadIdx.x == 0) part[blockIdx.x] = red[0];
}

// ---- scan level 2 ----
__global__ void kb_scan2(int* __restrict__ part, int nb, int* __restrict__ total_out)
{
    __shared__ int a[2048], b[2048];
    int t = threadIdx.x;
    for (int i = t; i < 2048; i += 1024) a[i] = (i < nb) ? part[i] : 0;
    __syncthreads();
    int* src = a; int* dst = b;
    for (int ofs = 1; ofs < 2048; ofs <<= 1) {
        for (int i = t; i < 2048; i += 1024)
            dst[i] = (i >= ofs) ? src[i] + src[i - ofs] : src[i];
        __syncthreads();
        int* tmp = src; src = dst; dst = tmp;
    }
    for (int i = t; i < 2048; i += 1024)
        if (i < nb) part[i] = (i == 0) ? 0 : src[i - 1];
    if (t == 0) *total_out = src[nb - 1];
}

// ---- scan level 3 ----
__global__ void kb_scan3(const unsigned* __restrict__ mask, const int* __restrict__ part,
                         int* __restrict__ row_start, int n)
{
    __shared__ int ts[256];
    int base = blockIdx.x * SCAN_B;
    int v[8];
    int sum = 0;
#pragma unroll
    for (int j = 0; j < 8; ++j) {
        int idx = base + threadIdx.x * 8 + j;
        v[j] = (idx < n) ? __popc(mask[idx]) : 0;
        sum += v[j];
    }
    ts[threadIdx.x] = sum;
    __syncthreads();
    for (int ofs = 1; ofs < 256; ofs <<= 1) {
        int add = (threadIdx.x >= ofs) ? ts[threadIdx.x - ofs] : 0;
        __syncthreads();
        ts[threadIdx.x] += add;
        __syncthreads();
    }
    int excl = (threadIdx.x == 0) ? 0 : ts[threadIdx.x - 1];
    excl += part[blockIdx.x];
#pragma unroll
    for (int j = 0; j < 8; ++j) {
        int idx = base + threadIdx.x * 8 + j;
        if (idx < n) row_start[idx] = excl;
        excl += v[j];
    }
}

// ---- build CSR entries, slot deterministic (k-ascending within row) ----
__global__ void kb_build(const int* __restrict__ gather, const int* __restrict__ scatter,
                         const unsigned* __restrict__ mask, const int* __restrict__ row_start,
                         int* __restrict__ list, int npair, int M, int vec_ok)
{
    int k = blockIdx.y;
    const int* sp = scatter + (size_t)k * npair;
    const int* gp = gather  + (size_t)k * npair;
    unsigned klow = (1u << k) - 1u;
    int t = blockIdx.x * blockDim.x + threadIdx.x;
    if (vec_ok) {
        int base = t * 4;
        if (base >= npair) return;
        int4 s4 = *(const int4*)(sp + base);
        int4 g4 = *(const int4*)(gp + base);
        if (s4.x < M) list[row_start[s4.x] + __popc(mask[s4.x] & klow)] = (k << 18) | g4.x;
        if (s4.y < M) list[row_start[s4.y] + __popc(mask[s4.y] & klow)] = (k << 18) | g4.y;
        if (s4.z < M) list[row_start[s4.z] + __popc(mask[s4.z] & klow)] = (k << 18) | g4.z;
        if (s4.w < M) list[row_start[s4.w] + __popc(mask[s4.w] & klow)] = (k << 18) | g4.w;
    } else {
        if (t >= npair) return;
        int s = sp[t];
        if (s < M) list[row_start[s] + __popc(mask[s] & klow)] = (k << 18) | gp[t];
    }
}

// ---- main: wave64 handles rows (2w, 2w+1) in LOCKSTEP (no half-wave divergence).
//      lane = (h = row half, o = cout). Joint loop to max(cnt0,cnt1); each half
//      clamps its entry index and zeroes its contribution when exhausted.
//      Every ds_read_b128 / feat load / dot2 serves 2 entries. ----
__global__ __launch_bounds__(1024, 8)
void kb_main(const uint4* __restrict__ featH, const uint4* __restrict__ wH,
             const int* __restrict__ row_start, const int* __restrict__ list,
             float* __restrict__ out, int M, int K)
{
    __shared__ uint4 wL[KMAX * 128];                 // 55296 B
    for (int i = threadIdx.x; i < K * 128; i += 1024) wL[i] = wH[i];
    __syncthreads();

    const int lane = threadIdx.x & 63;
    const int h    = lane >> 5;                      // row half (0/1)
    const int o    = lane & 31;                      // output channel

    int wid = (blockIdx.x * 1024 + threadIdx.x) >> 6;
    int nW  = (gridDim.x * 1024) >> 6;

    for (int mb = wid * 2; mb < M; mb += nW * 2) {
        const int m = mb + h;                        // this half's row
        int e0 = 0, cnt = 0;
        if (m < M) { e0 = row_start[m]; cnt = row_start[m + 1] - e0; }
        const int mc = max(cnt, __shfl_xor(cnt, 32, 64));   // wave-uniform bound

        float a0 = 0.f, a1 = 0.f, a2 = 0.f, a3 = 0.f;
        for (int i = 0; i < mc; ++i) {
            const bool valid = (i < cnt);
            const int e = e0 + (valid ? i : 0);      // clamp: row has >=1 entry
            const int pk = list[e];                  // uniform within half
            const int k = pk >> 18, g = pk & 0x3FFFF;
            const uint4* fr = featH + ((size_t)g << 2);
            uint4 f0 = fr[0], f1 = fr[1], f2 = fr[2], f3 = fr[3];   // broadcast/half
            const uint4* wr = wL + k * 128 + o;
            uint4 w0 = wr[0], w1 = wr[32], w2 = wr[64], w3 = wr[96];
            float s0 = 0.f, s1 = 0.f, s2 = 0.f, s3 = 0.f;
            s0 = dot2(f0.x, w0.x, s0); s0 = dot2(f0.y, w0.y, s0);
            s0 = dot2(f0.z, w0.z, s0); s0 = dot2(f0.w, w0.w, s0);
            s1 = dot2(f1.x, w1.x, s1); s1 = dot2(f1.y, w1.y, s1);
            s1 = dot2(f1.z, w1.z, s1); s1 = dot2(f1.w, w1.w, s1);
            s2 = dot2(f2.x, w2.x, s2); s2 = dot2(f2.y, w2.y, s2);
            s2 = dot2(f2.z, w2.z, s2); s2 = dot2(f2.w, w2.w, s2);
            s3 = dot2(f3.x, w3.x, s3); s3 = dot2(f3.y, w3.y, s3);
            s3 = dot2(f3.z, w3.z, s3); s3 = dot2(f3.w, w3.w, s3);
            a0 += valid ? s0 : 0.f;  a1 += valid ? s1 : 0.f;
            a2 += valid ? s2 : 0.f;  a3 += valid ? s3 : 0.f;
        }
        if (m < M) out[(size_t)m * COUT + o] = (a0 + a1) + (a2 + a3);
    }
}

// ---- fallback: atomic scatter (R1, proven) ----
__global__ __launch_bounds__(256, 4)
void spconv_scatter(const float* __restrict__ feat, const float* __restrict__ weight,
                    const int* __restrict__ gather, const int* __restrict__ scatter,
                    float* __restrict__ out, int npair, int M)
{
    const int k = blockIdx.y;
    const int lane = threadIdx.x & 31;
    const int sub = threadIdx.x >> 5;
    const int pairs_per_blk = blockDim.x >> 5;
    const float* wk = weight + (size_t)k * (CIN * COUT);
    float w[CIN];
#pragma unroll
    for (int i = 0; i < CIN; ++i) w[i] = wk[i * COUT + lane];
    const int* gk = gather + (size_t)k * npair;
    const int* sk = scatter + (size_t)k * npair;
    for (int p = blockIdx.x * pairs_per_blk + sub; p < npair; p += gridDim.x * pairs_per_blk) {
        int s = sk[p];
        if (s >= M) continue;
        int g = gk[p];
        const float4* fr = (const float4*)(feat + (size_t)g * CIN);
        float a = 0.f;
#pragma unroll
        for (int c = 0; c < 8; ++c) {
            float4 f4 = fr[c];
            a = fmaf(f4.x, w[4*c+0], a); a = fmaf(f4.y, w[4*c+1], a);
            a = fmaf(f4.z, w[4*c+2], a); a = fmaf(f4.w, w[4*c+3], a);
        }
        atomicAdd(&out[(size_t)s * COUT + lane], a);
    }
}

extern "C" void kernel_launch(void* const* d_in, const int* in_sizes, int n_in,
                              void* d_out, int out_size, void* d_ws, size_t ws_size,
                              hipStream_t stream)
{
    const float* feat    = (const float*)d_in[0];
    const float* weight  = (const float*)d_in[1];
    const int*   gather  = (const int*)d_in[2];
    const int*   scatter = (const int*)d_in[3];
    float*       out     = (float*)d_out;

    const int N     = in_sizes[0] / CIN;            // input sites (150000)
    const int K     = in_sizes[1] / (CIN * COUT);   // 27
    const int npair = in_sizes[2] / K;              // 150000
    const int M     = out_size / COUT;              // num_out (~2.13M)
    const int NB    = (M + SCAN_B - 1) / SCAN_B;    // scan blocks (~1041)
    const int vec_ok = ((npair & 3) == 0) ? 1 : 0;

    // workspace: mask | row_start | part | wH | fH | list
    uintptr_t base = (uintptr_t)d_ws;
    auto align256 = [](uintptr_t p) { return (p + 255) & ~(uintptr_t)255; };
    uintptr_t p_mask = align256(base);                             // M uints
    uintptr_t p_rs   = align256(p_mask + (size_t)M * 4);           // M+1 ints
    uintptr_t p_part = align256(p_rs + ((size_t)M + 1) * 4);       // 2048 ints
    uintptr_t p_wH   = align256(p_part + 2048 * 4);                // K*512 uints
    uintptr_t p_fH   = align256(p_wH + (size_t)K * 512 * 4);       // N*16 uints
    uintptr_t p_list = align256(p_fH + (size_t)N * 16 * 4);        // K*npair ints
    uintptr_t p_end  = p_list + (size_t)K * npair * 4;

    if (p_end - base > ws_size || NB > 2048 || K > KMAX || N > 0x40000) {
        hipMemsetAsync(d_out, 0, (size_t)out_size * sizeof(float), stream);
        dim3 grid(160, K);
        spconv_scatter<<<grid, 256, 0, stream>>>(feat, weight, gather, scatter, out, npair, M);
        return;
    }

    unsigned* mask      = (unsigned*)p_mask;
    int*      row_start = (int*)p_rs;
    int*      part      = (int*)p_part;
    unsigned* wH        = (unsigned*)p_wH;
    unsigned* fH        = (unsigned*)p_fH;
    int*      list      = (int*)p_list;

    hipMemsetAsync(mask, 0, (size_t)M * 4, stream);

    k_fuse<<<2048, 256, 0, stream>>>(weight, feat, scatter, wH, fH, mask,
                                     K, N, npair, M, vec_ok);

    kb_scan1<<<NB, 256, 0, stream>>>(mask, part, M);
    kb_scan2<<<1, 1024, 0, stream>>>(part, NB, row_start + M);
    kb_scan3<<<NB, 256, 0, stream>>>(mask, part, row_start, M);

    const int pthreads = vec_ok ? npair / 4 : npair;
    dim3 gp((pthreads + 255) / 256, K);
    kb_build<<<gp, 256, 0, stream>>>(gather, scatter, mask, row_start, list,
                                     npair, M, vec_ok);

    kb_main<<<512, 1024, 0, stream>>>((const uint4*)fH, (const uint4*)wH,
                                      row_start, list, out, M, K);
}